// Round 1
// baseline (496.107 us; speedup 1.0000x reference)
//
#include <hip/hip_runtime.h>
#include <hip/hip_bf16.h>

typedef unsigned short u16;
typedef unsigned int   u32;
typedef short short8  __attribute__((ext_vector_type(8)));
typedef float floatx4 __attribute__((ext_vector_type(4)));

#define MFMA(a, b, c) __builtin_amdgcn_mfma_f32_16x16x32_bf16((a), (b), (c), 0, 0, 0)

static __device__ __forceinline__ u16 f2bf(float f) {
  __hip_bfloat16 h = __float2bfloat16(f);
  return *reinterpret_cast<u16*>(&h);
}
static __device__ __forceinline__ float bf2f(u16 u) {
  __hip_bfloat16 h = *reinterpret_cast<__hip_bfloat16*>(&u);
  return __bfloat162float(h);
}

// async global->LDS, 16B per lane; LDS dest must be lane-contiguous (m104/m108)
static __device__ __forceinline__ void gll16(const void* g, void* l) {
  __builtin_amdgcn_global_load_lds(
      (const __attribute__((address_space(1))) u32*)g,
      (__attribute__((address_space(3))) u32*)l, 16, 0, 0);
}

// ---------------------------------------------------------------------------
// Kernel 1: convert x fp32 -> bf16 (8*2048*2048 = 33,554,432 elems)
// ---------------------------------------------------------------------------
__global__ void convert_x_kernel(const float4* __restrict__ x, u16* __restrict__ xb) {
  int idx = blockIdx.x * blockDim.x + threadIdx.x;
  int stride = gridDim.x * blockDim.x;
  for (int i = idx; i < 8388608; i += stride) {
    float4 v = x[i];
    ushort4 o;
    o.x = f2bf(v.x); o.y = f2bf(v.y); o.z = f2bf(v.z); o.w = f2bf(v.w);
    ((ushort4*)xb)[i] = o;
  }
}

// ---------------------------------------------------------------------------
// Kernel 2: Wt[768][2048] bf16 = concat(Wq,Wk,Wv) transposed ([2048][256] each)
// ---------------------------------------------------------------------------
__global__ void build_wt_kernel(const float* __restrict__ Wq, const float* __restrict__ Wk,
                                const float* __restrict__ Wv, u16* __restrict__ Wt) {
  int n = blockIdx.x;              // 0..767
  int sel = n >> 8, nc = n & 255;
  const float* W = (sel == 0) ? Wq : (sel == 1) ? Wk : Wv;
  for (int kk = threadIdx.x; kk < 2048; kk += 256)
    Wt[(size_t)n * 2048 + kk] = f2bf(W[(size_t)kk * 256 + nc]);
}

// ---------------------------------------------------------------------------
// Kernel 3: QKV GEMM. C[16384,768] = Xb[16384,2048] @ Wt[768,2048]^T  (m97-style)
// 128x128 tile, BK=32, 256 thr, 4 waves each 64x64. Outputs:
//   q,k -> row-major bf16 [16384][256]; v -> transposed bf16 [b][256][2048]
// ---------------------------------------------------------------------------
__global__ __launch_bounds__(256, 2) void qkv_gemm_kernel(
    const u16* __restrict__ xb, const u16* __restrict__ Wt,
    const float* __restrict__ bq, const float* __restrict__ bk, const float* __restrict__ bv,
    u16* __restrict__ qws, u16* __restrict__ kws, u16* __restrict__ vtws) {
  __shared__ __align__(16) u16 As[128 * 32];
  __shared__ __align__(16) u16 Bs[128 * 32];
  const int t = threadIdx.x;
  const int lane = t & 63, w = t >> 6;
  const int ln = lane & 15, quad = lane >> 4;
  const int wm = w >> 1, wn = w & 1;
  const int m0 = blockIdx.x * 128;
  const int n0 = blockIdx.y * 128;

  // staging: chunk ch (16B) = row*4 + c ; thread handles ch = t and t+256
  const int rowS = t >> 2, cS = t & 3;
  const u16* pa0 = xb + (size_t)(m0 + rowS) * 2048 + cS * 8;
  const u16* pb0 = Wt + (size_t)(n0 + rowS) * 2048 + cS * 8;

  floatx4 acc[4][4] = {};

  for (int kt = 0; kt < 64; ++kt) {
    const int ko = kt * 32;
    gll16(pa0 + ko,               As + (size_t)t * 8);
    gll16(pa0 + ko + 64 * 2048,   As + (size_t)(t + 256) * 8);
    gll16(pb0 + ko,               Bs + (size_t)t * 8);
    gll16(pb0 + ko + 64 * 2048,   Bs + (size_t)(t + 256) * 8);
    __syncthreads();

    short8 af[4], bf[4];
#pragma unroll
    for (int rt = 0; rt < 4; ++rt)
      af[rt] = *(const short8*)&As[(wm * 64 + rt * 16 + ln) * 32 + quad * 8];
#pragma unroll
    for (int ct = 0; ct < 4; ++ct)
      bf[ct] = *(const short8*)&Bs[(wn * 64 + ct * 16 + ln) * 32 + quad * 8];
#pragma unroll
    for (int rt = 0; rt < 4; ++rt)
#pragma unroll
      for (int ct = 0; ct < 4; ++ct)
        acc[rt][ct] = MFMA(af[rt], bf[ct], acc[rt][ct]);
    __syncthreads();
  }

  // epilogue: bias + store. region uniform per block (n0 spans one of q/k/v)
  const int region = n0 >> 8;  // 0=q 1=k 2=v
#pragma unroll
  for (int rt = 0; rt < 4; ++rt) {
    const int mg = m0 + wm * 64 + rt * 16 + quad * 4;
#pragma unroll
    for (int ct = 0; ct < 4; ++ct) {
      const int colg = n0 + wn * 64 + ct * 16 + ln;
      const int nc = colg & 255;
      const float bias = (region == 0) ? bq[nc] : (region == 1) ? bk[nc] : bv[nc];
#pragma unroll
      for (int i = 0; i < 4; ++i) {
        const int m = mg + i;
        const u16 us = f2bf(acc[rt][ct][i] + bias);
        if (region == 0)      qws[(size_t)m * 256 + nc] = us;
        else if (region == 1) kws[(size_t)m * 256 + nc] = us;
        else vtws[((size_t)((m >> 11) * 256 + nc)) * 2048 + (m & 2047)] = us;
      }
    }
  }
}

// ---------------------------------------------------------------------------
// Kernel 4: fused attention.
// Grid (32 qtiles, 8 batches), 256 thr = 4 waves in 2x2 (wq = q-half of 32 rows,
// wk = key-half of 32 keys for S / d-half of 128 for PV). BM=64, BN=64.
// z = sigmoid(s)/16 in [0,1/16] -> no max subtraction: O = sum(exp(z) v)/sum(exp(z)).
// LDS XOR-swizzle (16B chunk ^= row&7) -> 2-way conflicts only (free, m136).
// pbuf/dbuf alias kbuf (S-phase done with kbuf before P write) to fit 64KB.
// ---------------------------------------------------------------------------
__global__ __launch_bounds__(256, 1) void attn_kernel(
    const u16* __restrict__ qws, const u16* __restrict__ kws,
    const u16* __restrict__ vtws, float* __restrict__ out) {
  __shared__ __align__(16) u16 kbuf[64 * 256];   // 32 KB (aliased by pbuf+dbuf)
  __shared__ __align__(16) u16 vbuf[256 * 64];   // 32 KB
  u16*   pbuf = kbuf;                            // 64*64 u16 = 8 KB
  float* dbuf = (float*)(kbuf + 64 * 64);        // 2*64 floats

  const int t = threadIdx.x;
  const int lane = t & 63, w = t >> 6;
  const int ln = lane & 15, quad = lane >> 4;
  const int wq = w >> 1, wk = w & 1;
  const int sw = ln & 7;                         // common row-swizzle bits
  const int b = blockIdx.y;
  const int q0 = blockIdx.x * 64;

  // persistent Q fragments: wave's 32 rows x 256 feats (A-layout, m=ln, k=quad*8+j)
  short8 qf[2][8];
  const u16* qbase = qws + ((size_t)(b * 2048 + q0 + wq * 32)) * 256;
#pragma unroll
  for (int rt = 0; rt < 2; ++rt)
#pragma unroll
    for (int kk = 0; kk < 8; ++kk)
      qf[rt][kk] = *(const short8*)(qbase + (size_t)(rt * 16 + ln) * 256 + kk * 32 + quad * 8);

  floatx4 of[2][8] = {};
  float pdn[2][4] = {};

  const u16* kbase = kws + ((size_t)b * 2048) * 256;
  const u16* vbase = vtws + ((size_t)b * 256) * 2048;
  const int ck = t & 31, rk = t >> 5;   // kbuf staging coords
  const int cv = t & 7,  rv = t >> 3;   // vbuf staging coords

  for (int kt = 0; kt < 32; ++kt) {
    // ---- stage K tile [64][256] and V^T tile [256][64], swizzled ----
#pragma unroll
    for (int i = 0; i < 8; ++i) {
      const int row = i * 8 + rk;
      uint4 d = *(const uint4*)(kbase + (((size_t)(kt * 64 + row)) << 8) + ck * 8);
      *(uint4*)&kbuf[(row << 8) + ((ck ^ (row & 7)) << 3)] = d;
    }
#pragma unroll
    for (int i = 0; i < 8; ++i) {
      const int row = i * 32 + rv;
      uint4 d = *(const uint4*)(vbase + (((size_t)row) << 11) + (kt << 6) + cv * 8);
      *(uint4*)&vbuf[(row << 6) + ((cv ^ (row & 7)) << 3)] = d;
    }
    __syncthreads();

    // ---- S = Q K^T : wave computes S[32 rows][32 keys] ----
    floatx4 sacc[2][2] = {};
    const int key0 = wk * 32 + ln, key1 = key0 + 16;
#pragma unroll
    for (int kk = 0; kk < 8; ++kk) {
      const int cr = (kk << 2) + quad;
      short8 b0 = *(const short8*)&kbuf[(key0 << 8) + ((cr ^ sw) << 3)];
      short8 b1 = *(const short8*)&kbuf[(key1 << 8) + ((cr ^ sw) << 3)];
      sacc[0][0] = MFMA(qf[0][kk], b0, sacc[0][0]);
      sacc[1][0] = MFMA(qf[1][kk], b0, sacc[1][0]);
      sacc[0][1] = MFMA(qf[0][kk], b1, sacc[0][1]);
      sacc[1][1] = MFMA(qf[1][kk], b1, sacc[1][1]);
    }
    __syncthreads();  // all waves done reading kbuf before pbuf (alias) write

    // ---- p = exp(sigmoid(s)/16); row sums; write P to LDS (bf16) ----
#pragma unroll
    for (int rt = 0; rt < 2; ++rt) {
      float rs[4] = {0.f, 0.f, 0.f, 0.f};
#pragma unroll
      for (int ct = 0; ct < 2; ++ct) {
        const int keyl = wk * 32 + ct * 16 + ln;
        const int kc = keyl >> 3, klow = keyl & 7;
#pragma unroll
        for (int i = 0; i < 4; ++i) {
          const float s = sacc[rt][ct][i];
          const float sig = __builtin_amdgcn_rcpf(1.f + __expf(-s));
          const float p = __expf(0.0625f * sig);
          const u16 pb = f2bf(p);
          rs[i] += bf2f(pb);  // denom from the same rounded values fed to MFMA
          const int rowl = wq * 32 + rt * 16 + (quad << 2) + i;
          pbuf[(rowl << 6) + ((kc ^ (rowl & 7)) << 3) + klow] = pb;
        }
      }
#pragma unroll
      for (int i = 0; i < 4; ++i) {
        float v = rs[i];
        v += __shfl_xor(v, 1); v += __shfl_xor(v, 2);
        v += __shfl_xor(v, 4); v += __shfl_xor(v, 8);
        pdn[rt][i] += v;
      }
    }
    __syncthreads();  // pbuf visible to all waves

    // ---- O += P V : wave computes O[32 rows][128 d (wk half)] ----
    const int rA0 = wq * 32 + ln, rA1 = rA0 + 16;
#pragma unroll
    for (int ks = 0; ks < 2; ++ks) {
      const int cr = (ks << 2) + quad;
      short8 a0 = *(const short8*)&pbuf[(rA0 << 6) + ((cr ^ sw) << 3)];
      short8 a1 = *(const short8*)&pbuf[(rA1 << 6) + ((cr ^ sw) << 3)];
#pragma unroll
      for (int dt = 0; dt < 8; ++dt) {
        const int dr = wk * 128 + dt * 16 + ln;
        short8 vb = *(const short8*)&vbuf[(dr << 6) + ((cr ^ sw) << 3)];
        of[0][dt] = MFMA(a0, vb, of[0][dt]);
        of[1][dt] = MFMA(a1, vb, of[1][dt]);
      }
    }
    __syncthreads();  // done with pbuf/vbuf before next stage overwrites
  }

  // ---- combine denominators across wk halves via LDS ----
  if (ln == 0) {
#pragma unroll
    for (int rt = 0; rt < 2; ++rt)
#pragma unroll
      for (int i = 0; i < 4; ++i)
        dbuf[wk * 64 + wq * 32 + rt * 16 + (quad << 2) + i] = pdn[rt][i];
  }
  __syncthreads();

  // ---- normalize + store fp32 output ----
#pragma unroll
  for (int rt = 0; rt < 2; ++rt) {
#pragma unroll
    for (int i = 0; i < 4; ++i) {
      const int rowl = wq * 32 + rt * 16 + (quad << 2) + i;
      const float inv = 1.f / (dbuf[rowl] + dbuf[64 + rowl]);
      float* orow = out + ((size_t)(b * 2048 + q0 + rowl)) * 256 + wk * 128 + ln;
#pragma unroll
      for (int dt = 0; dt < 8; ++dt)
        orow[dt * 16] = of[rt][dt][i] * inv;
    }
  }
}

// ---------------------------------------------------------------------------
// launch
// ---------------------------------------------------------------------------
extern "C" void kernel_launch(void* const* d_in, const int* in_sizes, int n_in,
                              void* d_out, int out_size, void* d_ws, size_t ws_size,
                              hipStream_t stream) {
  const float* x  = (const float*)d_in[0];
  const float* Wq = (const float*)d_in[1];
  const float* bq = (const float*)d_in[2];
  const float* Wk = (const float*)d_in[3];
  const float* bk = (const float*)d_in[4];
  const float* Wv = (const float*)d_in[5];
  const float* bv = (const float*)d_in[6];
  float* out = (float*)d_out;

  char* ws = (char*)d_ws;
  // ws layout (bytes): xb 67108864 | Wt 3145728 | q 8388608 | k 8388608 | vt 8388608
  u16* xb   = (u16*)(ws);
  u16* Wt   = (u16*)(ws + 67108864);
  u16* qws  = (u16*)(ws + 70254592);
  u16* kws  = (u16*)(ws + 78643200);
  u16* vtws = (u16*)(ws + 87031808);   // total 95,420,416 B

  convert_x_kernel<<<4096, 256, 0, stream>>>((const float4*)x, xb);
  build_wt_kernel<<<768, 256, 0, stream>>>(Wq, Wk, Wv, Wt);
  qkv_gemm_kernel<<<dim3(128, 6), 256, 0, stream>>>(xb, Wt, bq, bk, bv, qws, kws, vtws);
  attn_kernel<<<dim3(32, 8), 256, 0, stream>>>(qws, kws, vtws, out);
}